// Round 1
// baseline (9.967 us; speedup 1.0000x reference)
//
#include <hip/hip_runtime.h>
#include <math.h>

#define H 128

__device__ __forceinline__ float wave_reduce_sum(float v) {
    // full 64-lane wavefront reduction (CDNA wave = 64, not 32)
    #pragma unroll
    for (int m = 32; m >= 1; m >>= 1) v += __shfl_xor(v, m, 64);
    return v;
}

__device__ __forceinline__ float sigmoidf(float x) {
    return 1.0f / (1.0f + __expf(-x));
}

// One block per output element j (128 blocks). 3 waves per block;
// wave w handles gate row (j + 128*w): w=0 -> r, w=1 -> z, w=2 -> n.
// Keep x-part and h-part separate (n gate needs n_x + r*n_h).
__global__ __launch_bounds__(192) void gru_fwd_cell_kernel(
    const float* __restrict__ x,      // (512,)
    const float* __restrict__ h0,     // (2,1,128) -> forward dir = h0[0..127]
    const float* __restrict__ w_ih,   // (384,512) row-major
    const float* __restrict__ w_hh,   // (384,128) row-major
    const float* __restrict__ b_ih,   // (384,)
    const float* __restrict__ b_hh,   // (384,)
    float* __restrict__ out)          // (128,)
{
    const int j    = blockIdx.x;        // output index 0..127
    const int tid  = threadIdx.x;       // 0..191
    const int wave = tid >> 6;          // 0..2
    const int lane = tid & 63;          // 0..63

    const int row = j + (wave << 7);    // gate row in [0,384)

    // ---- w_ih[row] . x : 512 floats = 128 float4; lanes take f4 idx lane, lane+64
    const float4* wih4 = reinterpret_cast<const float4*>(w_ih + (size_t)row * 512);
    const float4* x4   = reinterpret_cast<const float4*>(x);
    float accX = 0.0f;
    #pragma unroll
    for (int s = 0; s < 2; ++s) {
        const int idx = lane + (s << 6);
        float4 wv = wih4[idx];
        float4 xv = x4[idx];
        accX += wv.x * xv.x + wv.y * xv.y + wv.z * xv.z + wv.w * xv.w;
    }

    // ---- w_hh[row] . h : 128 floats = 64 float2; lane takes f2 idx lane
    const float2* whh2 = reinterpret_cast<const float2*>(w_hh + (size_t)row * H);
    const float2* h2   = reinterpret_cast<const float2*>(h0);  // forward dir starts at 0
    float accH;
    {
        float2 wv = whh2[lane];
        float2 hv = h2[lane];
        accH = wv.x * hv.x + wv.y * hv.y;
    }

    accX = wave_reduce_sum(accX);
    accH = wave_reduce_sum(accH);

    __shared__ float sX[3];
    __shared__ float sH[3];
    if (lane == 0) {
        sX[wave] = accX;
        sH[wave] = accH;
    }
    __syncthreads();

    if (tid == 0) {
        const float hj = h0[j];  // forward hidden state element
        const float r = sigmoidf(sX[0] + b_ih[j]       + sH[0] + b_hh[j]);
        const float z = sigmoidf(sX[1] + b_ih[j + 128] + sH[1] + b_hh[j + 128]);
        const float n = tanhf(sX[2] + b_ih[j + 256] + r * (sH[2] + b_hh[j + 256]));
        out[j] = (1.0f - z) * n + z * hj;
    }
}

extern "C" void kernel_launch(void* const* d_in, const int* in_sizes, int n_in,
                              void* d_out, int out_size, void* d_ws, size_t ws_size,
                              hipStream_t stream) {
    const float* x    = (const float*)d_in[0];   // (1,512)
    const float* h0   = (const float*)d_in[1];   // (2,1,128)
    const float* w_ih = (const float*)d_in[2];   // (384,512)
    const float* w_hh = (const float*)d_in[3];   // (384,128)
    const float* b_ih = (const float*)d_in[4];   // (384,)
    const float* b_hh = (const float*)d_in[5];   // (384,)
    float* out = (float*)d_out;                  // (1,128)

    gru_fwd_cell_kernel<<<H, 192, 0, stream>>>(x, h0, w_ih, w_hh, b_ih, b_hh, out);
}